// Round 2
// baseline (1069.870 us; speedup 1.0000x reference)
//
#include <hip/hip_runtime.h>
#include <hip/hip_bf16.h>

// ---------------------------------------------------------------------------
// Fused kernel for Model_84464826843698 on gfx950 — round 2.
// B=4, Cin=128, N=16384, K=16, MID=64, OUT=128, SHARE=8, PT=10
// One block = 4 positions, 512 threads (8 waves). LDS 53376 B -> >=2 blocks/CU.
// ---------------------------------------------------------------------------

typedef __attribute__((ext_vector_type(8))) short bf16x8;
typedef __attribute__((ext_vector_type(4))) float f32x4;
typedef __attribute__((ext_vector_type(4))) unsigned short us4;
typedef __attribute__((ext_vector_type(8))) unsigned short us8;

#define MFMA(a, b, c) __builtin_amdgcn_mfma_f32_16x16x32_bf16((a), (b), (c), 0, 0, 0)

// LDS map (bytes). Region reuse:
//   A: F (ph0-1) -> X2 + X1 + XFS (ph2+)
//   B: XN (ph1-2) -> X3 (ph3+)
//   H1 (ph2, per-wave) reused for PTF (ph2-3, same wave)
#define OFF_F   0       // [4 pos][16 kslot][272B: 128ch bf16 + pad], pos stride 4352
#define OFF_X2  0       // [4 pos][16 kslot][136B: 64ch bf16 + pad], pos stride 2176
#define OFF_X1  8704    // [4 pos][64] f32, pos stride 256
#define OFF_XFS 9728    // [4 pos][2048B: 1024 c' bf16], c' = mid*16+k
#define OFF_XN  17920   // [4][16][272B], pos stride 4352
#define OFF_X3  17920   // [4 pos][64 mid][48B: 16 k bf16 + pad], pos stride 3072
#define OFF_P   35328   // [4][16 kslot][64B: 32 p bf16 (>=10 zero)], pos stride 1024
#define OFF_H1  39424   // [4][16 kslot][144B: 64 mid bf16 + pad], pos stride 2304 (reused: PTF)
#define OFF_HP  48640   // [8 wave][32] f32 partials
#define OFF_HB  49664   // [8 j][4 pos] f32
#define OFF_WS  49792   // [4 pos][8 j2][16 k] f32 softmax
#define OFF_OM  51840   // [4 pos][128B: 64 mid bf16]
#define OFF_XC  52352   // [4 pos][256B: 128 ch bf16] identity
#define SMEM_BYTES 53376

__device__ __forceinline__ unsigned short f2b(float f) {
    union { __hip_bfloat16 h; unsigned short u; } v;
    v.h = __float2bfloat16(f);
    return v.u;
}
__device__ __forceinline__ float b2f(unsigned short u) {
    union { unsigned short u; __hip_bfloat16 h; } v;
    v.u = u;
    return __bfloat162float(v.h);
}
// 8 consecutive fp32 -> bf16x8 A-fragment
__device__ __forceinline__ bf16x8 ldw8(const float* p) {
    f32x4 a = *(const f32x4*)p, c = *(const f32x4*)(p + 4);
    bf16x8 r;
    r[0] = (short)f2b(a[0]); r[1] = (short)f2b(a[1]);
    r[2] = (short)f2b(a[2]); r[3] = (short)f2b(a[3]);
    r[4] = (short)f2b(c[0]); r[5] = (short)f2b(c[1]);
    r[6] = (short)f2b(c[2]); r[7] = (short)f2b(c[3]);
    return r;
}
__device__ __forceinline__ us4 pk4(float a, float b, float c, float d) {
    us4 r; r[0] = f2b(a); r[1] = f2b(b); r[2] = f2b(c); r[3] = f2b(d); return r;
}

__global__ __launch_bounds__(512, 4)
void fused_model_kernel(const float* __restrict__ feats, const float* __restrict__ ppfs,
                        const float* __restrict__ w0, const float* __restrict__ b0,
                        const float* __restrict__ w1, const float* __restrict__ b1,
                        const float* __restrict__ w2, const float* __restrict__ b2,
                        const float* __restrict__ w3, const float* __restrict__ b3,
                        const float* __restrict__ cw1, const float* __restrict__ cw2,
                        const float* __restrict__ cb2, const float* __restrict__ wo,
                        const float* __restrict__ bo, const float* __restrict__ p1,
                        const float* __restrict__ p2, float* __restrict__ out) {
    extern __shared__ char smem[];
    const int tid = threadIdx.x;
    const int W = tid >> 6;        // wave 0..7
    const int lane = tid & 63;
    const int kk = lane & 15;      // MFMA row/col index
    const int g = lane >> 4;       // MFMA k-group
    const int bid = blockIdx.x;
    const int b = bid >> 12;       // 4096 n-tiles per batch
    const int n0 = (bid & 4095) * 4;

    // ---------------- Phase 0: stage feats + ppfs (fp32 -> bf16) ------------
    {
        const int kq = tid & 3, ci = (tid >> 2) & 127;
        #pragma unroll
        for (int it = 0; it < 4; ++it) {
            const float* src = feats + (((size_t)b * 128 + ci) * 16384 + (n0 + it)) * 16 + kq * 4;
            f32x4 v = *(const f32x4*)src;
            char* dst = smem + OFF_F + it * 4352 + ci * 2;
            *(unsigned short*)(dst + (kq * 4 + 0) * 272) = f2b(v[0]);
            *(unsigned short*)(dst + (kq * 4 + 1) * 272) = f2b(v[1]);
            *(unsigned short*)(dst + (kq * 4 + 2) * 272) = f2b(v[2]);
            *(unsigned short*)(dst + (kq * 4 + 3) * 272) = f2b(v[3]);
        }
        if (tid < 160) {                       // 4 pos x 10 p x 4 kq
            int pos = tid / 40, r = tid % 40, p = r >> 2, kq2 = r & 3;
            const float* src = ppfs + (((size_t)b * 10 + p) * 16384 + (n0 + pos)) * 16 + kq2 * 4;
            f32x4 v = *(const f32x4*)src;
            char* dst = smem + OFF_P + pos * 1024 + p * 2;
            *(unsigned short*)(dst + (kq2 * 4 + 0) * 64) = f2b(v[0]);
            *(unsigned short*)(dst + (kq2 * 4 + 1) * 64) = f2b(v[1]);
            *(unsigned short*)(dst + (kq2 * 4 + 2) * 64) = f2b(v[2]);
            *(unsigned short*)(dst + (kq2 * 4 + 3) * 64) = f2b(v[3]);
        } else if (tid >= 192) {               // zero p = 10..31: 11 dwords x 64 rows
            for (int z = tid - 192; z < 704; z += 320) {
                int pos = z / 176, rr = z % 176, k2 = rr / 11, dwi = rr % 11;
                *(unsigned*)(smem + OFF_P + pos * 1024 + k2 * 64 + 20 + dwi * 4) = 0u;
            }
        }
    }
    __syncthreads();

    // ---------------- Phase 1: conv0 -> relu -> XN (+ identity XC) ----------
    {
        bf16x8 af[4];
        #pragma unroll
        for (int kt = 0; kt < 4; ++kt) af[kt] = ldw8(w0 + (16 * W + kk) * 128 + kt * 32 + 8 * g);
        f32x4 bv = *(const f32x4*)(b0 + 16 * W + 4 * g);
        #pragma unroll
        for (int pos = 0; pos < 4; ++pos) {
            f32x4 acc = {0.f, 0.f, 0.f, 0.f};
            #pragma unroll
            for (int kt = 0; kt < 4; ++kt) {
                bf16x8 bf = *(const bf16x8*)(smem + OFF_F + pos * 4352 + kk * 272 + (kt * 32 + 8 * g) * 2);
                acc = MFMA(af[kt], bf, acc);
            }
            us4 xw = pk4(fmaxf(acc[0] + bv[0], 0.f), fmaxf(acc[1] + bv[1], 0.f),
                         fmaxf(acc[2] + bv[2], 0.f), fmaxf(acc[3] + bv[3], 0.f));
            *(us4*)(smem + OFF_XN + pos * 4352 + kk * 272 + (16 * W + 4 * g) * 2) = xw;
            if (kk == 0) *(us4*)(smem + OFF_XC + pos * 256 + (16 * W + 4 * g) * 2) = xw;
        }
    }
    __syncthreads();

    // ---------------- Phase 2: pt1->pt2->conv3 (w0-3) | conv2,x1 (w4-7) -----
    f32x4 acc3[4];   // conv3 accumulators, held across barrier by waves 0-3
    if (W < 4) {
        const int pos = W;
        // pt1: H1[kslot][mid] = relu(p1 @ P)   (k = p, padded 10->32 w/ zeros)
        bf16x8 bp = *(const bf16x8*)(smem + OFF_P + pos * 1024 + kk * 64 + 16 * g);
        #pragma unroll
        for (int mt = 0; mt < 4; ++mt) {
            bf16x8 ap;
            #pragma unroll
            for (int j = 0; j < 8; ++j) {
                int p = 8 * g + j;
                ap[j] = (short)((p < 10) ? f2b(p1[(16 * mt + kk) * 10 + p]) : (unsigned short)0);
            }
            f32x4 acc = {0.f, 0.f, 0.f, 0.f};
            acc = MFMA(ap, bp, acc);
            *(us4*)(smem + OFF_H1 + pos * 2304 + kk * 144 + (16 * mt + 4 * g) * 2) =
                pk4(fmaxf(acc[0], 0.f), fmaxf(acc[1], 0.f), fmaxf(acc[2], 0.f), fmaxf(acc[3], 0.f));
        }
        // pt2 -> accp, then spill to PTF (reusing H1 region; same-wave only)
        {
            bf16x8 bh[2];
            #pragma unroll
            for (int kt = 0; kt < 2; ++kt)
                bh[kt] = *(const bf16x8*)(smem + OFF_H1 + pos * 2304 + kk * 144 + (kt * 32 + 8 * g) * 2);
            f32x4 accp[4];
            #pragma unroll
            for (int mt = 0; mt < 4; ++mt) {
                f32x4 a = {0.f, 0.f, 0.f, 0.f};
                #pragma unroll
                for (int kt = 0; kt < 2; ++kt)
                    a = MFMA(ldw8(p2 + (16 * mt + kk) * 64 + kt * 32 + 8 * g), bh[kt], a);
                accp[mt] = a;
            }
            #pragma unroll
            for (int mt = 0; mt < 4; ++mt)
                *(us4*)(smem + OFF_H1 + pos * 2304 + kk * 144 + (16 * mt + 4 * g) * 2) =
                    pk4(accp[mt][0], accp[mt][1], accp[mt][2], accp[mt][3]);
        }
        // conv3 -> acc3 (kept in registers across the barrier)
        {
            bf16x8 bx[4];
            #pragma unroll
            for (int kt = 0; kt < 4; ++kt)
                bx[kt] = *(const bf16x8*)(smem + OFF_XN + pos * 4352 + kk * 272 + (kt * 32 + 8 * g) * 2);
            #pragma unroll
            for (int mt = 0; mt < 4; ++mt) {
                f32x4 a = {0.f, 0.f, 0.f, 0.f};
                #pragma unroll
                for (int kt = 0; kt < 4; ++kt)
                    a = MFMA(ldw8(w3 + (16 * mt + kk) * 128 + kt * 32 + 8 * g), bx[kt], a);
                acc3[mt] = a;
            }
        }
    } else {
        const int pos = W - 4;
        // conv2 + bias -> X2
        bf16x8 bx[4];
        #pragma unroll
        for (int kt = 0; kt < 4; ++kt)
            bx[kt] = *(const bf16x8*)(smem + OFF_XN + pos * 4352 + kk * 272 + (kt * 32 + 8 * g) * 2);
        #pragma unroll
        for (int mt = 0; mt < 4; ++mt) {
            f32x4 a = {0.f, 0.f, 0.f, 0.f};
            #pragma unroll
            for (int kt = 0; kt < 4; ++kt)
                a = MFMA(ldw8(w2 + (16 * mt + kk) * 128 + kt * 32 + 8 * g), bx[kt], a);
            f32x4 bv = *(const f32x4*)(b2 + 16 * mt + 4 * g);
            *(us4*)(smem + OFF_X2 + pos * 2176 + kk * 136 + (16 * mt + 4 * g) * 2) =
                pk4(a[0] + bv[0], a[1] + bv[1], a[2] + bv[2], a[3] + bv[3]);
        }
        // x1 = conv1 @ xn[:, k=0]: wave 4+i does row-block i, cols = pos (kk&3)
        {
            int mt = W - 4;
            f32x4 a = {0.f, 0.f, 0.f, 0.f};
            #pragma unroll
            for (int kt = 0; kt < 4; ++kt) {
                bf16x8 bf = *(const bf16x8*)(smem + OFF_XN + (kk & 3) * 4352 + (kt * 32 + 8 * g) * 2);
                a = MFMA(ldw8(w1 + (16 * mt + kk) * 128 + kt * 32 + 8 * g), bf, a);
            }
            if (kk < 4) {
                f32x4 bv = *(const f32x4*)(b1 + 16 * mt + 4 * g);
                f32x4 x1v = {a[0] + bv[0], a[1] + bv[1], a[2] + bv[2], a[3] + bv[3]};
                *(f32x4*)(smem + OFF_X1 + kk * 256 + (16 * mt + 4 * g) * 4) = x1v;
            }
        }
    }
    __syncthreads();

    // ---------------- Phase 3: combine -> X3, XFS (waves 0-3) ---------------
    if (W < 4) {
        const int pos = W;
        #pragma unroll
        for (int mt = 0; mt < 4; ++mt) {
            f32x4 b3v = *(const f32x4*)(b3 + 16 * mt + 4 * g);
            #pragma unroll
            for (int r = 0; r < 4; ++r) {
                int mid = 16 * mt + 4 * g + r;
                float ptf = b2f(*(const unsigned short*)(smem + OFF_H1 + pos * 2304 + kk * 144 + mid * 2));
                float x2v = b2f(*(const unsigned short*)(smem + OFF_X2 + pos * 2176 + kk * 136 + mid * 2));
                float x1v = *(const float*)(smem + OFF_X1 + pos * 256 + mid * 4);
                float x3 = acc3[mt][r] + b3v[r] + ptf;
                float xfs = x1v - x2v + ptf;
                *(unsigned short*)(smem + OFF_X3 + pos * 3072 + mid * 48 + kk * 2) = f2b(x3);
                *(unsigned short*)(smem + OFF_XFS + pos * 2048 + (mid * 16 + kk) * 2) = f2b(xfs);
            }
        }
    }
    __syncthreads();

    // ---------------- Phase 4: h[j,pos] = relu(cw1[j,:] . XFS) --------------
    {
        const int half = lane >> 5, jj = (lane >> 2) & 7, pos = lane & 3;
        const int c0 = W * 128 + half * 64;
        const float* wr = cw1 + jj * 1024 + c0;
        const char* xb = smem + OFF_XFS + pos * 2048 + c0 * 2;
        float s = 0.f;
        #pragma unroll
        for (int cc = 0; cc < 64; cc += 4) {
            us4 xv = *(const us4*)(xb + cc * 2);
            f32x4 wv = *(const f32x4*)(wr + cc);
            s += wv[0] * b2f(xv[0]) + wv[1] * b2f(xv[1]) +
                 wv[2] * b2f(xv[2]) + wv[3] * b2f(xv[3]);
        }
        s += __shfl_xor(s, 32);
        if (lane < 32) *(float*)(smem + OFF_HP + W * 128 + lane * 4) = s;
    }
    __syncthreads();
    if (tid < 32) {
        float s = 0.f;
        #pragma unroll
        for (int ww = 0; ww < 8; ++ww) s += *(const float*)(smem + OFF_HP + ww * 128 + tid * 4);
        *(float*)(smem + OFF_HB + tid * 4) = fmaxf(s, 0.f);
    }
    __syncthreads();

    // ---------------- Phase 5: logits + softmax over k ----------------------
    {
        const int pos = tid >> 7, c = tid & 127, k = c & 15, j2 = c >> 4;
        float wl = cb2[c];
        f32x4 w20 = *(const f32x4*)(cw2 + c * 8);
        f32x4 w21 = *(const f32x4*)(cw2 + c * 8 + 4);
        #pragma unroll
        for (int j = 0; j < 4; ++j) {
            wl += w20[j] * *(const float*)(smem + OFF_HB + (j * 4 + pos) * 4);
            wl += w21[j] * *(const float*)(smem + OFF_HB + ((j + 4) * 4 + pos) * 4);
        }
        float mx = wl;
        for (int off = 8; off; off >>= 1) mx = fmaxf(mx, __shfl_xor(mx, off, 16));
        float e = __expf(wl - mx);
        float ss = e;
        for (int off = 8; off; off >>= 1) ss += __shfl_xor(ss, off, 16);
        *(float*)(smem + OFF_WS + pos * 512 + j2 * 64 + k * 4) = e / ss;
    }
    __syncthreads();

    // ---------------- Phase 6: om[m] = relu(sum_k w[m&7,k] * X3[m,k]) -------
    if (tid < 256) {
        const int pos = tid >> 6, m = tid & 63, j2 = m & 7;
        us8 x0 = *(const us8*)(smem + OFF_X3 + pos * 3072 + m * 48);
        us8 x1v = *(const us8*)(smem + OFF_X3 + pos * 3072 + m * 48 + 16);
        const float* wsp = (const float*)(smem + OFF_WS + pos * 512 + j2 * 64);
        float s = 0.f;
        #pragma unroll
        for (int i = 0; i < 8; ++i) s += wsp[i] * b2f(x0[i]);
        #pragma unroll
        for (int i = 0; i < 8; ++i) s += wsp[8 + i] * b2f(x1v[i]);
        *(unsigned short*)(smem + OFF_OM + pos * 128 + m * 2) = f2b(fmaxf(s, 0.f));
    }
    __syncthreads();

    // ---------------- Phase 7: convout + bias + identity -> out -------------
    {
        f32x4 acc = {0.f, 0.f, 0.f, 0.f};
        #pragma unroll
        for (int kt = 0; kt < 2; ++kt) {
            bf16x8 bf = *(const bf16x8*)(smem + OFF_OM + (kk & 3) * 128 + (kt * 32 + 8 * g) * 2);
            acc = MFMA(ldw8(wo + (16 * W + kk) * 64 + kt * 32 + 8 * g), bf, acc);
        }
        if (kk < 4) {
            f32x4 bv = *(const f32x4*)(bo + 16 * W + 4 * g);
            #pragma unroll
            for (int r = 0; r < 4; ++r) {
                int o = 16 * W + 4 * g + r;
                float v = acc[r] + bv[r] +
                          b2f(*(const unsigned short*)(smem + OFF_XC + kk * 256 + o * 2));
                out[((size_t)b * 128 + o) * 16384 + n0 + kk] = v;
            }
        }
    }
}

extern "C" void kernel_launch(void* const* d_in, const int* in_sizes, int n_in,
                              void* d_out, int out_size, void* d_ws, size_t ws_size,
                              hipStream_t stream) {
    (void)in_sizes; (void)n_in; (void)out_size; (void)d_ws; (void)ws_size;
    const float* feats = (const float*)d_in[0];
    const float* ppfs  = (const float*)d_in[1];
    const float* w0  = (const float*)d_in[2];
    const float* b0  = (const float*)d_in[3];
    const float* w1  = (const float*)d_in[4];
    const float* b1  = (const float*)d_in[5];
    const float* w2  = (const float*)d_in[6];
    const float* b2  = (const float*)d_in[7];
    const float* w3  = (const float*)d_in[8];
    const float* b3  = (const float*)d_in[9];
    const float* cw1 = (const float*)d_in[10];
    const float* cw2 = (const float*)d_in[11];
    const float* cb2 = (const float*)d_in[12];
    const float* wo  = (const float*)d_in[13];
    const float* bo  = (const float*)d_in[14];
    const float* p1  = (const float*)d_in[15];
    const float* p2  = (const float*)d_in[16];
    float* out = (float*)d_out;

    fused_model_kernel<<<dim3(16384), dim3(512), SMEM_BYTES, stream>>>(
        feats, ppfs, w0, b0, w1, b1, w2, b2, w3, b3, cw1, cw2, cb2, wo, bo, p1, p2, out);
}

// Round 3
// 330.839 us; speedup vs baseline: 3.2338x; 3.2338x over previous
//
#include <hip/hip_runtime.h>
#include <hip/hip_bf16.h>

// ---------------------------------------------------------------------------
// Fused kernel for Model_84464826843698 on gfx950 — round 3.
// B=4, Cin=128, N=16384, K=16, MID=64, OUT=128, SHARE=8, PT=10
// TP=8 positions/block, 512 threads (8 waves), LDS 80896 B -> 2 blocks/CU.
// Weights pre-converted to bf16 in d_ws by convert_weights (no per-block cvt).
// ---------------------------------------------------------------------------

typedef __attribute__((ext_vector_type(8))) short bf16x8;
typedef __attribute__((ext_vector_type(4))) float f32x4;
typedef __attribute__((ext_vector_type(4))) unsigned short us4;

#define MFMA(a, b, c) __builtin_amdgcn_mfma_f32_16x16x32_bf16((a), (b), (c), 0, 0, 0)

// ---- LDS map (bytes); overlays are timeline-checked ----
#define OFF_F    0      // [8 pos][16 kslot][272B: 128ch bf16+pad]  P0->P1   34816
#define OFF_X2   0      // [8][16][136B: 64 mid]                    P2->P4   17408
#define OFF_PTF  17408  // [8][16][136B]                            P2->P4   17408
#define OFF_XN   34816  // [8][16][272B]                            P1->P3   34816
#define OFF_X3   34816  // [8][16][136B]                            P4->P7   17408
#define OFF_XFS  52224  // [8][2080B: 1024 c'' bf16 + pad]          P4->P5   16640
#define OFF_P    69632  // [8][16][64B: 32 p bf16, >=10 zero]       P0->P2    8192
#define OFF_WS   69632  // [8 pos][8 j2][68B: 16 k f32 + pad]       P6->P7    4352
#define OFF_HP   73984  // [8 wave][8 j][8 pos] f32                 P5        2048
#define OFF_HB   76032  // [8 j][8 pos] f32                         P5->P6     256
#define OFF_OM   76288  // [8 pos][144B: 64 mid bf16 + pad]         P7->P8    1152
#define OFF_X1   77824  // [8 pos][128B: 64 mid bf16]               P2->P4    1024
#define OFF_XC   78848  // [8 pos][256B: 128 ch bf16] identity      P1->P8    2048
#define SMEM_BYTES 80896

// ---- d_ws element offsets (bf16) ----
#define WS_W0  0        // [128][128]
#define WS_W1  16384    // [64][128]
#define WS_W2  24576    // [64][128]
#define WS_W3  32768    // [64][128]
#define WS_P1  40960    // [64][32]  (p>=10 zero)
#define WS_P2  43008    // [64][64]
#define WS_CW1 47104    // [16][1024] permuted: [j][k*64+mid], j>=8 zero
#define WS_WO  63488    // [128][64]
#define WS_TOTAL 71680

__device__ __forceinline__ unsigned short f2b(float f) {
    union { __hip_bfloat16 h; unsigned short u; } v;
    v.h = __float2bfloat16(f);
    return v.u;
}
__device__ __forceinline__ float b2f(unsigned short u) {
    union { unsigned u; float f; } v;
    v.u = ((unsigned)u) << 16;
    return v.f;
}
__device__ __forceinline__ us4 pk4(float a, float b, float c, float d) {
    us4 r; r[0] = f2b(a); r[1] = f2b(b); r[2] = f2b(c); r[3] = f2b(d); return r;
}
__device__ __forceinline__ bf16x8 ldb(const unsigned short* p) {   // 16B bf16 frag
    return *(const bf16x8*)p;
}

__global__ __launch_bounds__(512, 1)
void convert_weights(const float* __restrict__ w0, const float* __restrict__ w1,
                     const float* __restrict__ w2, const float* __restrict__ w3,
                     const float* __restrict__ p1, const float* __restrict__ p2,
                     const float* __restrict__ cw1, const float* __restrict__ wo,
                     unsigned short* __restrict__ ws) {
    int i = blockIdx.x * 512 + threadIdx.x;
    if (i >= WS_TOTAL) return;
    float v;
    if (i < 16384)      v = w0[i];
    else if (i < 24576) v = w1[i - 16384];
    else if (i < 32768) v = w2[i - 24576];
    else if (i < 40960) v = w3[i - 32768];
    else if (i < 43008) { int r = i - 40960, row = r >> 5, k = r & 31;
                          v = (k < 10) ? p1[row * 10 + k] : 0.f; }
    else if (i < 47104) v = p2[i - 43008];
    else if (i < 63488) { int r = i - 47104, j = r >> 10, kc = r & 1023;
                          v = (j < 8) ? cw1[j * 1024 + (kc & 63) * 16 + (kc >> 6)] : 0.f; }
    else                v = wo[i - 63488];
    ws[i] = f2b(v);
}

__global__ __launch_bounds__(512, 4)
void fused_model_kernel(const float* __restrict__ feats, const float* __restrict__ ppfs,
                        const unsigned short* __restrict__ wsb,
                        const float* __restrict__ b0, const float* __restrict__ b1,
                        const float* __restrict__ b2, const float* __restrict__ b3,
                        const float* __restrict__ cw2, const float* __restrict__ cb2,
                        const float* __restrict__ bo, float* __restrict__ out) {
    extern __shared__ char smem[];
    const int tid = threadIdx.x;
    const int W = tid >> 6;
    const int lane = tid & 63;
    const int kk = lane & 15;     // MFMA row/col index
    const int g = lane >> 4;      // MFMA k-group
    const int bid = blockIdx.x;
    const int b = bid >> 11;
    const int n0 = (bid & 2047) * 8;

    // ---------------- P0: stage feats (transpose fp32->bf16) + ppfs ---------
    {
        const int kq = tid & 3, ci = tid >> 2;      // 4 x 128
        #pragma unroll
        for (int pos = 0; pos < 8; ++pos) {
            f32x4 v = *(const f32x4*)(feats + (((size_t)b * 128 + ci) * 16384 + (n0 + pos)) * 16 + kq * 4);
            char* base = smem + OFF_F + pos * 4352 + ci * 2;
            *(unsigned short*)(base + (kq * 4 + 0) * 272) = f2b(v[0]);
            *(unsigned short*)(base + (kq * 4 + 1) * 272) = f2b(v[1]);
            *(unsigned short*)(base + (kq * 4 + 2) * 272) = f2b(v[2]);
            *(unsigned short*)(base + (kq * 4 + 3) * 272) = f2b(v[3]);
        }
        if (tid < 320) {                            // 8 pos x 10 p x 4 kq
            int pos = tid / 40, r = tid % 40, p = r >> 2, kq2 = r & 3;
            f32x4 v = *(const f32x4*)(ppfs + (((size_t)b * 10 + p) * 16384 + (n0 + pos)) * 16 + kq2 * 4);
            char* base = smem + OFF_P + pos * 1024 + p * 2;
            *(unsigned short*)(base + (kq2 * 4 + 0) * 64) = f2b(v[0]);
            *(unsigned short*)(base + (kq2 * 4 + 1) * 64) = f2b(v[1]);
            *(unsigned short*)(base + (kq2 * 4 + 2) * 64) = f2b(v[2]);
            *(unsigned short*)(base + (kq2 * 4 + 3) * 64) = f2b(v[3]);
        } else {                                    // zero p=10..31 (11 dwords x 128 rows)
            for (int z = tid - 320; z < 1408; z += 192) {
                int pos = z / 176, rr = z % 176, ks = rr / 11, dw = rr % 11;
                *(unsigned*)(smem + OFF_P + pos * 1024 + ks * 64 + 20 + dw * 4) = 0u;
            }
        }
    }
    __syncthreads();

    // ---------------- P1: conv0 -> relu -> XN (+ identity XC) ---------------
    {
        bf16x8 a0[4];
        #pragma unroll
        for (int kt = 0; kt < 4; ++kt) a0[kt] = ldb(wsb + WS_W0 + (16 * W + kk) * 128 + kt * 32 + 8 * g);
        f32x4 bv = *(const f32x4*)(b0 + 16 * W + 4 * g);
        #pragma unroll
        for (int pos = 0; pos < 8; ++pos) {
            f32x4 acc = {0.f, 0.f, 0.f, 0.f};
            #pragma unroll
            for (int kt = 0; kt < 4; ++kt) {
                bf16x8 bf = *(const bf16x8*)(smem + OFF_F + pos * 4352 + kk * 272 + (kt * 32 + 8 * g) * 2);
                acc = MFMA(a0[kt], bf, acc);
            }
            us4 xw = pk4(fmaxf(acc[0] + bv[0], 0.f), fmaxf(acc[1] + bv[1], 0.f),
                         fmaxf(acc[2] + bv[2], 0.f), fmaxf(acc[3] + bv[3], 0.f));
            *(us4*)(smem + OFF_XN + pos * 4352 + kk * 272 + (16 * W + 4 * g) * 2) = xw;
            if (kk == 0) *(us4*)(smem + OFF_XC + pos * 256 + (16 * W + 4 * g) * 2) = xw;
        }
    }
    __syncthreads();

    // ---------------- P2: pt1 -> (reg transpose) -> pt2 (w0-3) | conv2 + x1 (w4-7)
    if (W < 4) {
        bf16x8 a1[4], a2[4][2];
        #pragma unroll
        for (int mt = 0; mt < 4; ++mt) {
            a1[mt] = ldb(wsb + WS_P1 + (16 * mt + kk) * 32 + 8 * g);
            a2[mt][0] = ldb(wsb + WS_P2 + (16 * mt + kk) * 64 + 8 * g);
            a2[mt][1] = ldb(wsb + WS_P2 + (16 * mt + kk) * 64 + 32 + 8 * g);
        }
        const int sel = g >> 1;
        const int sa = kk + 16 * ((2 * g) & 3);
        const int sb = kk + 16 * ((2 * g + 1) & 3);
        #pragma unroll
        for (int pp = 0; pp < 2; ++pp) {
            const int pos = 2 * W + pp;
            bf16x8 bp = *(const bf16x8*)(smem + OFF_P + pos * 1024 + kk * 64 + 16 * g);
            int pkd[4][2];
            #pragma unroll
            for (int mt = 0; mt < 4; ++mt) {
                f32x4 hv = {0.f, 0.f, 0.f, 0.f};
                hv = MFMA(a1[mt], bp, hv);
                us4 t = pk4(fmaxf(hv[0], 0.f), fmaxf(hv[1], 0.f),
                            fmaxf(hv[2], 0.f), fmaxf(hv[3], 0.f));
                pkd[mt][0] = ((int*)&t)[0];
                pkd[mt][1] = ((int*)&t)[1];
            }
            // in-register transpose: C-layout(H1) -> B-frags for pt2
            union { int d[4]; bf16x8 v; } bh0, bh1;
            bh0.d[0] = sel ? __shfl(pkd[1][0], sa, 64) : __shfl(pkd[0][0], sa, 64);
            bh0.d[1] = sel ? __shfl(pkd[1][1], sa, 64) : __shfl(pkd[0][1], sa, 64);
            bh0.d[2] = sel ? __shfl(pkd[1][0], sb, 64) : __shfl(pkd[0][0], sb, 64);
            bh0.d[3] = sel ? __shfl(pkd[1][1], sb, 64) : __shfl(pkd[0][1], sb, 64);
            bh1.d[0] = sel ? __shfl(pkd[3][0], sa, 64) : __shfl(pkd[2][0], sa, 64);
            bh1.d[1] = sel ? __shfl(pkd[3][1], sa, 64) : __shfl(pkd[2][1], sa, 64);
            bh1.d[2] = sel ? __shfl(pkd[3][0], sb, 64) : __shfl(pkd[2][0], sb, 64);
            bh1.d[3] = sel ? __shfl(pkd[3][1], sb, 64) : __shfl(pkd[2][1], sb, 64);
            #pragma unroll
            for (int mt = 0; mt < 4; ++mt) {
                f32x4 acc = {0.f, 0.f, 0.f, 0.f};
                acc = MFMA(a2[mt][0], bh0.v, acc);
                acc = MFMA(a2[mt][1], bh1.v, acc);
                *(us4*)(smem + OFF_PTF + pos * 2176 + kk * 136 + (16 * mt + 4 * g) * 2) =
                    pk4(acc[0], acc[1], acc[2], acc[3]);
            }
        }
    } else {
        const int mt = W - 4;
        bf16x8 aw2[4], aw1[4];
        #pragma unroll
        for (int kt = 0; kt < 4; ++kt) {
            aw2[kt] = ldb(wsb + WS_W2 + (16 * mt + kk) * 128 + kt * 32 + 8 * g);
            aw1[kt] = ldb(wsb + WS_W1 + (16 * mt + kk) * 128 + kt * 32 + 8 * g);
        }
        f32x4 b2v = *(const f32x4*)(b2 + 16 * mt + 4 * g);
        #pragma unroll
        for (int pos = 0; pos < 8; ++pos) {
            f32x4 acc = {0.f, 0.f, 0.f, 0.f};
            #pragma unroll
            for (int kt = 0; kt < 4; ++kt) {
                bf16x8 bf = *(const bf16x8*)(smem + OFF_XN + pos * 4352 + kk * 272 + (kt * 32 + 8 * g) * 2);
                acc = MFMA(aw2[kt], bf, acc);
            }
            *(us4*)(smem + OFF_X2 + pos * 2176 + kk * 136 + (16 * mt + 4 * g) * 2) =
                pk4(acc[0] + b2v[0], acc[1] + b2v[1], acc[2] + b2v[2], acc[3] + b2v[3]);
        }
        // x1 = conv1 @ xn[:, k=0] + b1 : cols = pos (kk&7)
        f32x4 a1c = {0.f, 0.f, 0.f, 0.f};
        #pragma unroll
        for (int kt = 0; kt < 4; ++kt) {
            bf16x8 bf = *(const bf16x8*)(smem + OFF_XN + (kk & 7) * 4352 + (kt * 32 + 8 * g) * 2);
            a1c = MFMA(aw1[kt], bf, a1c);
        }
        if (kk < 8) {
            f32x4 b1v = *(const f32x4*)(b1 + 16 * mt + 4 * g);
            *(us4*)(smem + OFF_X1 + kk * 128 + (16 * mt + 4 * g) * 2) =
                pk4(a1c[0] + b1v[0], a1c[1] + b1v[1], a1c[2] + b1v[2], a1c[3] + b1v[3]);
        }
    }
    __syncthreads();

    // ---------------- P3: conv3 (all waves) -> acc3 regs --------------------
    f32x4 acc3[4];
    {
        const int mt = W & 3, ph = W >> 2;
        bf16x8 aw3[4];
        #pragma unroll
        for (int kt = 0; kt < 4; ++kt)
            aw3[kt] = ldb(wsb + WS_W3 + (16 * mt + kk) * 128 + kt * 32 + 8 * g);
        #pragma unroll
        for (int pp = 0; pp < 4; ++pp) {
            const int pos = ph * 4 + pp;
            f32x4 acc = {0.f, 0.f, 0.f, 0.f};
            #pragma unroll
            for (int kt = 0; kt < 4; ++kt) {
                bf16x8 bf = *(const bf16x8*)(smem + OFF_XN + pos * 4352 + kk * 272 + (kt * 32 + 8 * g) * 2);
                acc = MFMA(aw3[kt], bf, acc);
            }
            acc3[pp] = acc;
        }
    }
    __syncthreads();

    // ---------------- P4: combine -> X3, XFS (vectorized) -------------------
    {
        const int mt = W & 3, ph = W >> 2;
        f32x4 b3v = *(const f32x4*)(b3 + 16 * mt + 4 * g);
        #pragma unroll
        for (int pp = 0; pp < 4; ++pp) {
            const int pos = ph * 4 + pp;
            us4 ptfv = *(const us4*)(smem + OFF_PTF + pos * 2176 + kk * 136 + (16 * mt + 4 * g) * 2);
            us4 x2v  = *(const us4*)(smem + OFF_X2  + pos * 2176 + kk * 136 + (16 * mt + 4 * g) * 2);
            us4 x1v  = *(const us4*)(smem + OFF_X1  + pos * 128 + (16 * mt + 4 * g) * 2);
            float pf0 = b2f(ptfv[0]), pf1 = b2f(ptfv[1]), pf2 = b2f(ptfv[2]), pf3 = b2f(ptfv[3]);
            *(us4*)(smem + OFF_X3 + pos * 2176 + kk * 136 + (16 * mt + 4 * g) * 2) =
                pk4(acc3[pp][0] + b3v[0] + pf0, acc3[pp][1] + b3v[1] + pf1,
                    acc3[pp][2] + b3v[2] + pf2, acc3[pp][3] + b3v[3] + pf3);
            *(us4*)(smem + OFF_XFS + pos * 2080 + (kk * 64 + 16 * mt + 4 * g) * 2) =
                pk4(b2f(x1v[0]) - b2f(x2v[0]) + pf0, b2f(x1v[1]) - b2f(x2v[1]) + pf1,
                    b2f(x1v[2]) - b2f(x2v[2]) + pf2, b2f(x1v[3]) - b2f(x2v[3]) + pf3);
        }
    }
    __syncthreads();

    // ---------------- P5: h partials via MFMA (wave W = k-range) ------------
    {
        bf16x8 acw[4];
        #pragma unroll
        for (int kt = 0; kt < 4; ++kt)
            acw[kt] = ldb(wsb + WS_CW1 + kk * 1024 + W * 128 + kt * 32 + 8 * g);
        f32x4 acc = {0.f, 0.f, 0.f, 0.f};
        #pragma unroll
        for (int kt = 0; kt < 4; ++kt) {
            bf16x8 bf = *(const bf16x8*)(smem + OFF_XFS + (kk & 7) * 2080 + (W * 128 + kt * 32 + 8 * g) * 2);
            acc = MFMA(acw[kt], bf, acc);
        }
        if (kk < 8 && g < 2) {
            #pragma unroll
            for (int r = 0; r < 4; ++r)
                *(float*)(smem + OFF_HP + W * 256 + ((4 * g + r) * 8 + kk) * 4) = acc[r];
        }
    }
    __syncthreads();
    if (tid < 64) {
        float s = 0.f;
        #pragma unroll
        for (int w = 0; w < 8; ++w) s += *(const float*)(smem + OFF_HP + w * 256 + tid * 4);
        *(float*)(smem + OFF_HB + tid * 4) = fmaxf(s, 0.f);
    }
    __syncthreads();

    // ---------------- P6: logits + softmax over k ---------------------------
    {
        #pragma unroll
        for (int pp = 0; pp < 2; ++pp) {
            const int item = tid + 512 * pp;
            const int pos = item >> 7, c = item & 127, k = c & 15, j2 = c >> 4;
            float wl = cb2[c];
            f32x4 w20 = *(const f32x4*)(cw2 + c * 8);
            f32x4 w21 = *(const f32x4*)(cw2 + c * 8 + 4);
            #pragma unroll
            for (int j = 0; j < 4; ++j) {
                wl += w20[j] * *(const float*)(smem + OFF_HB + (j * 8 + pos) * 4);
                wl += w21[j] * *(const float*)(smem + OFF_HB + ((j + 4) * 8 + pos) * 4);
            }
            float mx = wl;
            for (int off = 8; off; off >>= 1) mx = fmaxf(mx, __shfl_xor(mx, off, 16));
            float e = __expf(wl - mx);
            float ss = e;
            for (int off = 8; off; off >>= 1) ss += __shfl_xor(ss, off, 16);
            *(float*)(smem + OFF_WS + pos * 544 + j2 * 68 + k * 4) = e / ss;
        }
    }
    __syncthreads();

    // ---------------- P7: om[m] = relu(sum_k w[m&7,k] * X3[k][m]) -----------
    {
        const int pos = W, m = lane, j2 = m & 7;
        const char* wsp = smem + OFF_WS + pos * 544 + j2 * 68;
        const char* x3b = smem + OFF_X3 + pos * 2176 + m * 2;
        float s = 0.f;
        #pragma unroll
        for (int k = 0; k < 16; ++k)
            s += *(const float*)(wsp + k * 4) * b2f(*(const unsigned short*)(x3b + k * 136));
        *(unsigned short*)(smem + OFF_OM + pos * 144 + m * 2) = f2b(fmaxf(s, 0.f));
    }
    __syncthreads();

    // ---------------- P8: convout + bias + identity -> out ------------------
    {
        f32x4 acc = {0.f, 0.f, 0.f, 0.f};
        #pragma unroll
        for (int kt = 0; kt < 2; ++kt) {
            bf16x8 bf = *(const bf16x8*)(smem + OFF_OM + (kk & 7) * 144 + (kt * 32 + 8 * g) * 2);
            acc = MFMA(ldb(wsb + WS_WO + (16 * W + kk) * 64 + kt * 32 + 8 * g), bf, acc);
        }
        if (kk < 8) {
            f32x4 bv = *(const f32x4*)(bo + 16 * W + 4 * g);
            #pragma unroll
            for (int r = 0; r < 4; ++r) {
                int o = 16 * W + 4 * g + r;
                out[((size_t)b * 128 + o) * 16384 + n0 + kk] =
                    acc[r] + bv[r] + b2f(*(const unsigned short*)(smem + OFF_XC + kk * 256 + o * 2));
            }
        }
    }
}

extern "C" void kernel_launch(void* const* d_in, const int* in_sizes, int n_in,
                              void* d_out, int out_size, void* d_ws, size_t ws_size,
                              hipStream_t stream) {
    (void)in_sizes; (void)n_in; (void)out_size; (void)ws_size;
    const float* feats = (const float*)d_in[0];
    const float* ppfs  = (const float*)d_in[1];
    const float* w0  = (const float*)d_in[2];
    const float* b0  = (const float*)d_in[3];
    const float* w1  = (const float*)d_in[4];
    const float* b1  = (const float*)d_in[5];
    const float* w2  = (const float*)d_in[6];
    const float* b2  = (const float*)d_in[7];
    const float* w3  = (const float*)d_in[8];
    const float* b3  = (const float*)d_in[9];
    const float* cw1 = (const float*)d_in[10];
    const float* cw2 = (const float*)d_in[11];
    const float* cb2 = (const float*)d_in[12];
    const float* wo  = (const float*)d_in[13];
    const float* bo  = (const float*)d_in[14];
    const float* p1  = (const float*)d_in[15];
    const float* p2  = (const float*)d_in[16];
    float* out = (float*)d_out;
    unsigned short* wsb = (unsigned short*)d_ws;

    convert_weights<<<dim3((WS_TOTAL + 511) / 512), dim3(512), 0, stream>>>(
        w0, w1, w2, w3, p1, p2, cw1, wo, wsb);

    (void)hipFuncSetAttribute(reinterpret_cast<const void*>(fused_model_kernel),
                              hipFuncAttributeMaxDynamicSharedMemorySize, SMEM_BYTES);
    fused_model_kernel<<<dim3(8192), dim3(512), SMEM_BYTES, stream>>>(
        feats, ppfs, wsb, b0, b1, b2, b3, cw2, cb2, bo, out);
}